// Round 3
// baseline (2451.333 us; speedup 1.0000x reference)
//
#include <hip/hip_runtime.h>
#include <hip/hip_bf16.h>
#include <stdint.h>

#define B_   64
#define T_   512
#define NIN_ 256
#define N_   512
#define PP   192   // W_hh k-pairs held in VGPR per neuron (k = 0..383)
#define GP   64    // W_hh k-pairs streamed from L2 per step (k = 384..511)

typedef _Float16 half2_t __attribute__((ext_vector_type(2)));

#if defined(__has_builtin)
#if __has_builtin(__builtin_amdgcn_fdot2)
#define HAVE_FDOT2 1
#endif
#endif

__device__ __forceinline__ float dot2acc(unsigned int a, unsigned int b, float c) {
#ifdef HAVE_FDOT2
  return __builtin_amdgcn_fdot2(__builtin_bit_cast(half2_t, a),
                                __builtin_bit_cast(half2_t, b), c, false);
#else
  half2_t ha = __builtin_bit_cast(half2_t, a), hb = __builtin_bit_cast(half2_t, b);
  c += (float)ha[0] * (float)hb[0];
  c += (float)ha[1] * (float)hb[1];
  return c;
#endif
}

__device__ __forceinline__ float fast_tanh(float x) {
  float e = __expf(2.0f * x);
  return 1.0f - 2.0f / (e + 1.0f);
}

__device__ __forceinline__ unsigned int packh2(float a, float b) {
  half2_t h;
  h[0] = (_Float16)a;
  h[1] = (_Float16)b;
  return __builtin_bit_cast(unsigned int, h);
}

// ---------------- Phase 0: pack W_hh f32 -> f16-pair u32 [512][256] -------
__global__ __launch_bounds__(256) void packw(const float* __restrict__ Whh,
                                             unsigned int* __restrict__ pw) {
  const int i = blockIdx.x * 256 + threadIdx.x;   // 0..131071
  float2 v = *(const float2*)(Whh + 2 * (size_t)i);
  pw[i] = packh2(v.x, v.y);
}

// ---------------- Phase 1: xp[b,t,n] = sum_c x[b,t,c] * Wih[n,c] -> out ----
__global__ __launch_bounds__(256) void xproj(const float* __restrict__ x,
                                             const float* __restrict__ Wih,
                                             float* __restrict__ out) {
  const int tid = threadIdx.x;
  const int bm = blockIdx.x;
  const int bn = blockIdx.y;
  const int tm = tid & 15;
  const int tn = tid >> 4;
  const int m0 = bm << 7;
  const int n0 = bn << 7;

  __shared__ float xt[32][132];
  __shared__ float wt[32][132];

  float acc[8][8];
#pragma unroll
  for (int i = 0; i < 8; ++i)
#pragma unroll
    for (int j = 0; j < 8; ++j) acc[i][j] = 0.f;

  for (int ko = 0; ko < NIN_; ko += 32) {
#pragma unroll
    for (int it = 0; it < 4; ++it) {
      const int fidx = it * 256 + tid;
      const int mm = fidx >> 3;
      const int k4 = (fidx & 7) << 2;
      const float4 vx = *(const float4*)(x + (size_t)(m0 + mm) * NIN_ + ko + k4);
      xt[k4 + 0][mm] = vx.x; xt[k4 + 1][mm] = vx.y;
      xt[k4 + 2][mm] = vx.z; xt[k4 + 3][mm] = vx.w;
      const float4 vw = *(const float4*)(Wih + (size_t)(n0 + mm) * NIN_ + ko + k4);
      wt[k4 + 0][mm] = vw.x; wt[k4 + 1][mm] = vw.y;
      wt[k4 + 2][mm] = vw.z; wt[k4 + 3][mm] = vw.w;
    }
    __syncthreads();
#pragma unroll 4
    for (int kk = 0; kk < 32; ++kk) {
      float a[8], b[8];
      *(float4*)&a[0] = *(const float4*)&xt[kk][8 * tm];
      *(float4*)&a[4] = *(const float4*)&xt[kk][8 * tm + 4];
      *(float4*)&b[0] = *(const float4*)&wt[kk][8 * tn];
      *(float4*)&b[4] = *(const float4*)&wt[kk][8 * tn + 4];
#pragma unroll
      for (int i = 0; i < 8; ++i)
#pragma unroll
        for (int j = 0; j < 8; ++j) acc[i][j] = fmaf(a[i], b[j], acc[i][j]);
    }
    __syncthreads();
  }

#pragma unroll
  for (int i = 0; i < 8; ++i) {
    float4 v0 = make_float4(acc[i][0], acc[i][1], acc[i][2], acc[i][3]);
    float4 v1 = make_float4(acc[i][4], acc[i][5], acc[i][6], acc[i][7]);
    float* p = out + (size_t)(m0 + 8 * tm + i) * N_ + n0 + 8 * tn;
    *(float4*)p = v0;
    *((float4*)p + 1) = v1;
  }
}

// ---------------- Phase 2: recurrent scan, one block per batch ------------
// 64 blocks x 512 threads. Thread n owns neuron n: 192 weight-pairs in VGPR,
// 64 pairs re-read from L2 each step (same lines every step -> L2-hot).
// tanh(h) lives in LDS as 256 packed f16x2, read via single-address uniform
// uint4 broadcasts (conflict-free). One barrier per step. No cross-block
// communication at all.
__global__ __launch_bounds__(512, 2) void rnn_scan(const unsigned int* __restrict__ pw,
                                                   float* __restrict__ out) {
  const int b = blockIdx.x;
  const int n = threadIdx.x;
  float* outb = out + (size_t)b * T_ * N_;

  // VGPR weights: pairs 0..191 of packed row n
  const uint4* pwr = (const uint4*)(pw + (size_t)n * (N_ / 2));
  unsigned int w[PP];
#pragma unroll
  for (int j4 = 0; j4 < PP / 4; ++j4) {
    uint4 v = pwr[j4];
    w[4 * j4 + 0] = v.x; w[4 * j4 + 1] = v.y;
    w[4 * j4 + 2] = v.z; w[4 * j4 + 3] = v.w;
  }
  const uint4* gwr = pwr + PP / 4;   // pairs 192..255 (16 uint4, L2-resident)

  __shared__ __align__(16) unsigned int thp[2][N_ / 2];  // tanh(h) f16x2, dbuf

  // init thp[0] from h0 = out[b][0][:] (written by xproj; kernel boundary)
  if (n < 256) {
    float2 h0 = *(const float2*)(outb + 2 * n);
    thp[0][n] = packh2(fast_tanh(h0.x), fast_tanh(h0.y));
  }
  __syncthreads();

  for (int t = 1; t < T_; ++t) {
    float xp = outb[(size_t)t * N_ + n];   // prefetch; consumed after dots

    const uint4* tq = (const uint4*)thp[(t - 1) & 1];
    float acc = 0.f;

    // VGPR-weight part: pairs 0..191, tanh via uniform uint4 broadcast
#pragma unroll
    for (int j4 = 0; j4 < PP / 4; ++j4) {
      uint4 tv = tq[j4];
      acc = dot2acc(w[4 * j4 + 0], tv.x, acc);
      acc = dot2acc(w[4 * j4 + 1], tv.y, acc);
      acc = dot2acc(w[4 * j4 + 2], tv.z, acc);
      acc = dot2acc(w[4 * j4 + 3], tv.w, acc);
    }

    // L2-weight part: pairs 192..255, 4 chunks to bound live registers
#pragma unroll 1
    for (int c = 0; c < 4; ++c) {
      uint4 g0 = gwr[4 * c + 0];
      uint4 g1 = gwr[4 * c + 1];
      uint4 g2 = gwr[4 * c + 2];
      uint4 g3 = gwr[4 * c + 3];
      uint4 t0 = tq[PP / 4 + 4 * c + 0];
      uint4 t1 = tq[PP / 4 + 4 * c + 1];
      uint4 t2 = tq[PP / 4 + 4 * c + 2];
      uint4 t3 = tq[PP / 4 + 4 * c + 3];
      acc = dot2acc(g0.x, t0.x, acc);
      acc = dot2acc(g0.y, t0.y, acc);
      acc = dot2acc(g0.z, t0.z, acc);
      acc = dot2acc(g0.w, t0.w, acc);
      acc = dot2acc(g1.x, t1.x, acc);
      acc = dot2acc(g1.y, t1.y, acc);
      acc = dot2acc(g1.z, t1.z, acc);
      acc = dot2acc(g1.w, t1.w, acc);
      acc = dot2acc(g2.x, t2.x, acc);
      acc = dot2acc(g2.y, t2.y, acc);
      acc = dot2acc(g2.z, t2.z, acc);
      acc = dot2acc(g2.w, t2.w, acc);
      acc = dot2acc(g3.x, t3.x, acc);
      acc = dot2acc(g3.y, t3.y, acc);
      acc = dot2acc(g3.z, t3.z, acc);
      acc = dot2acc(g3.w, t3.w, acc);
    }

    const float y = acc + xp;
    const float th = fast_tanh(y);
    __builtin_nontemporal_store(y, &outb[(size_t)t * N_ + n]);

    const float thn = __shfl_xor(th, 1);
    if ((n & 1) == 0) thp[t & 1][n >> 1] = packh2(th, thn);

    __syncthreads();   // publish thp[t&1] for step t+1
  }
}

extern "C" void kernel_launch(void* const* d_in, const int* in_sizes, int n_in,
                              void* d_out, int out_size, void* d_ws, size_t ws_size,
                              hipStream_t stream) {
  const float* x   = (const float*)d_in[0];
  const float* Wih = (const float*)d_in[1];
  const float* Whh = (const float*)d_in[2];
  float* out = (float*)d_out;
  unsigned int* pw = (unsigned int*)d_ws;   // 512 KiB packed W_hh

  packw<<<512, 256, 0, stream>>>(Whh, pw);
  dim3 g1(256, 4);
  xproj<<<g1, 256, 0, stream>>>(x, Wih, out);
  rnn_scan<<<B_, 512, 0, stream>>>(pw, out);
}

// Round 4
// 760.171 us; speedup vs baseline: 3.2247x; 3.2247x over previous
//
#include <hip/hip_runtime.h>
#include <hip/hip_bf16.h>
#include <stdint.h>

#define B_   64
#define T_   512
#define NIN_ 256
#define N_   512

typedef _Float16 half2_t __attribute__((ext_vector_type(2)));

#if defined(__has_builtin)
#if __has_builtin(__builtin_amdgcn_fdot2)
#define HAVE_FDOT2 1
#endif
#endif

__device__ __forceinline__ float dot2acc(unsigned int a, unsigned int b, float c) {
#ifdef HAVE_FDOT2
  return __builtin_amdgcn_fdot2(__builtin_bit_cast(half2_t, a),
                                __builtin_bit_cast(half2_t, b), c, false);
#else
  half2_t ha = __builtin_bit_cast(half2_t, a), hb = __builtin_bit_cast(half2_t, b);
  c += (float)ha[0] * (float)hb[0];
  c += (float)ha[1] * (float)hb[1];
  return c;
#endif
}

__device__ __forceinline__ float fast_tanh(float x) {
  float e = __expf(2.0f * x);
  return 1.0f - 2.0f / (e + 1.0f);
}

__device__ __forceinline__ unsigned int packh2(float a, float b) {
  half2_t h;
  h[0] = (_Float16)a;
  h[1] = (_Float16)b;
  return __builtin_bit_cast(unsigned int, h);
}

// Quarter-interleaved LDS index for tanh pair p (p = k>>1, p in [0,256)):
// u32 index = j4*16 + q*4 + e  where j4=(p>>2)&15, q=p>>6, e=p&3.
// A wave's ds_read_b128 at {j4 fixed, q=lane&3} then hits 4 distinct
// addresses 16B apart -> disjoint bank quads -> conflict-free broadcast.
__device__ __forceinline__ int thp_idx(int p) {
  return (((p >> 2) & 15) << 4) + ((p >> 6) << 2) + (p & 3);
}

// ---------------- Phase 1: xp[b,t,n] = sum_c x[b,t,c] * Wih[n,c] -> out ----
__global__ __launch_bounds__(256) void xproj(const float* __restrict__ x,
                                             const float* __restrict__ Wih,
                                             float* __restrict__ out) {
  const int tid = threadIdx.x;
  const int bm = blockIdx.x;
  const int bn = blockIdx.y;
  const int tm = tid & 15;
  const int tn = tid >> 4;
  const int m0 = bm << 7;
  const int n0 = bn << 7;

  __shared__ float xt[32][132];
  __shared__ float wt[32][132];

  float acc[8][8];
#pragma unroll
  for (int i = 0; i < 8; ++i)
#pragma unroll
    for (int j = 0; j < 8; ++j) acc[i][j] = 0.f;

  for (int ko = 0; ko < NIN_; ko += 32) {
#pragma unroll
    for (int it = 0; it < 4; ++it) {
      const int fidx = it * 256 + tid;
      const int mm = fidx >> 3;
      const int k4 = (fidx & 7) << 2;
      const float4 vx = *(const float4*)(x + (size_t)(m0 + mm) * NIN_ + ko + k4);
      xt[k4 + 0][mm] = vx.x; xt[k4 + 1][mm] = vx.y;
      xt[k4 + 2][mm] = vx.z; xt[k4 + 3][mm] = vx.w;
      const float4 vw = *(const float4*)(Wih + (size_t)(n0 + mm) * NIN_ + ko + k4);
      wt[k4 + 0][mm] = vw.x; wt[k4 + 1][mm] = vw.y;
      wt[k4 + 2][mm] = vw.z; wt[k4 + 3][mm] = vw.w;
    }
    __syncthreads();
#pragma unroll 4
    for (int kk = 0; kk < 32; ++kk) {
      float a[8], b[8];
      *(float4*)&a[0] = *(const float4*)&xt[kk][8 * tm];
      *(float4*)&a[4] = *(const float4*)&xt[kk][8 * tm + 4];
      *(float4*)&b[0] = *(const float4*)&wt[kk][8 * tn];
      *(float4*)&b[4] = *(const float4*)&wt[kk][8 * tn + 4];
#pragma unroll
      for (int i = 0; i < 8; ++i)
#pragma unroll
        for (int j = 0; j < 8; ++j) acc[i][j] = fmaf(a[i], b[j], acc[i][j]);
    }
    __syncthreads();
  }

#pragma unroll
  for (int i = 0; i < 8; ++i) {
    float4 v0 = make_float4(acc[i][0], acc[i][1], acc[i][2], acc[i][3]);
    float4 v1 = make_float4(acc[i][4], acc[i][5], acc[i][6], acc[i][7]);
    float* p = out + (size_t)(m0 + 8 * tm + i) * N_ + n0 + 8 * tn;
    *(float4*)p = v0;
    *((float4*)p + 1) = v1;
  }
}

// ---------------- Phase 2: recurrent scan ---------------------------------
// 256 blocks x 512 threads. XCD-local mapping: the 4 slice-blocks of batch b
// all have blockIdx == b (mod 8) -> same XCD under round-robin dispatch ->
// exchange lives in that XCD's local L2 (correct either way; fast if mapping
// holds). Lane layout: 4 lanes per neuron (k-quarters), 64 weight-u32/lane
// (the size hipcc provably keeps in VGPR). Reduce via shfl_xor -> ONE
// barrier per step. Pre-activation y (f32, tagged) is published immediately
// after the reduce; readers tanh it themselves during their poll slot.
__global__ __launch_bounds__(512) void rnn_scan(const float* __restrict__ Whh,
                                                float* __restrict__ out,
                                                unsigned long long* __restrict__ ex) {
  const int blk = blockIdx.x;
  const int xcd = blk & 7;
  const int rest = blk >> 3;
  const int m = rest & 3;                 // slice 0..3 (128 neurons)
  const int b = xcd + ((rest >> 2) << 3); // batch 0..63, == blk (mod 8)
  const int tid = threadIdx.x;
  const int wv = tid >> 6;
  const int lane = tid & 63;
  const int q = lane & 3;                 // k-quarter
  const int nn = wv * 16 + (lane >> 2);   // neuron-in-slice 0..127
  const int gn = m * 128 + nn;            // global neuron

  __shared__ __align__(16) unsigned int thp[2][256];  // tanh(h) f16x2, dbuf

  float* outb = out + (size_t)b * T_ * N_;
  unsigned long long* exb = ex + (size_t)b * 1024;    // [2 slots][512]

  // weights: pairs k = q*128 .. q*128+127 of row gn -> 64 packed u32
  unsigned int w[64];
  {
    const float* wr = Whh + (size_t)gn * N_ + q * 128;
#pragma unroll
    for (int j = 0; j < 64; ++j) {
      float2 v = *(const float2*)(wr + 2 * j);
      w[j] = packh2(v.x, v.y);
    }
  }

  // init thp[0] from h_1 = out[b][0][:] (written by xproj; kernel boundary)
  if (tid < 256) {
    float2 h0 = *(const float2*)(outb + 2 * tid);
    thp[0][thp_idx(tid)] = packh2(fast_tanh(h0.x), fast_tanh(h0.y));
  }

  // poller assignment: tid<384 polls one remote neuron's published y
  const int pv = tid & 127;
  const int sr = tid >> 7;                 // 0..2 for pollers
  const int sm = sr + (sr >= m ? 1 : 0);   // actual remote slice
  const int prn = sm * 128 + pv;           // remote global neuron

  __syncthreads();

  for (int t = 1; t < T_; ++t) {
    // xp prefetch (q0 lanes; consumed after the reduce)
    float xp = 0.f;
    if (q == 0) xp = outb[(size_t)t * N_ + gn];

    // poll remote y_{t-1}, tanh it, pack into thp[(t-1)&1]
    if (t >= 2 && tid < 384) {
      unsigned long long v;
      do {
        v = __hip_atomic_load(&exb[((t - 1) & 1) * 512 + prn],
                              __ATOMIC_RELAXED, __HIP_MEMORY_SCOPE_AGENT);
      } while ((unsigned int)(v >> 32) != (unsigned int)(t - 1));
      const float th = fast_tanh(__uint_as_float((unsigned int)v));
      const float thn = __shfl_xor(th, 1);
      if ((tid & 1) == 0) thp[(t - 1) & 1][thp_idx(prn >> 1)] = packh2(th, thn);
    }
    __syncthreads();   // A: thp[(t-1)&1] complete

    const uint4* tq = (const uint4*)&thp[(t - 1) & 1][0];
    float acc = 0.f;
#pragma unroll
    for (int j4 = 0; j4 < 16; ++j4) {
      const uint4 tv = tq[j4 * 4 + q];   // 4 distinct addrs, disjoint banks
      acc = dot2acc(w[4 * j4 + 0], tv.x, acc);
      acc = dot2acc(w[4 * j4 + 1], tv.y, acc);
      acc = dot2acc(w[4 * j4 + 2], tv.z, acc);
      acc = dot2acc(w[4 * j4 + 3], tv.w, acc);
    }
    acc += __shfl_xor(acc, 1);
    acc += __shfl_xor(acc, 2);   // all 4 quarter-lanes now hold the full dot

    float th_own = 0.f;
    if (q == 0) {
      const float y = acc + xp;
      // publish FIRST: this is the cross-CU critical path
      __hip_atomic_store(&exb[(t & 1) * 512 + gn],
                         ((unsigned long long)(unsigned int)t << 32) |
                             (unsigned long long)__float_as_uint(y),
                         __ATOMIC_RELAXED, __HIP_MEMORY_SCOPE_AGENT);
      __builtin_nontemporal_store(y, &outb[(size_t)t * N_ + gn]);
      th_own = fast_tanh(y);
    }
    const float th_nb = __shfl_xor(th_own, 4);   // neighbor neuron's tanh
    if ((lane & 7) == 0)                          // q==0 and even neuron
      thp[t & 1][thp_idx(gn >> 1)] = packh2(th_own, th_nb);
    // no trailing barrier: next iteration's barrier A provides separation
    // (readers of thp[t&1] are all post-A(t+1); dbuf protects stragglers)
  }
}

extern "C" void kernel_launch(void* const* d_in, const int* in_sizes, int n_in,
                              void* d_out, int out_size, void* d_ws, size_t ws_size,
                              hipStream_t stream) {
  const float* x   = (const float*)d_in[0];
  const float* Wih = (const float*)d_in[1];
  const float* Whh = (const float*)d_in[2];
  float* out = (float*)d_out;
  unsigned long long* ex = (unsigned long long*)d_ws;

  // exchange buffer: 64 batches x 2 slots x 512 y-entries x 8B = 512 KiB
  hipMemsetAsync(d_ws, 0, (size_t)B_ * 2 * 512 * 8, stream);

  dim3 g1(256, 4);
  xproj<<<g1, 256, 0, stream>>>(x, Wih, out);
  rnn_scan<<<256, 512, 0, stream>>>(Whh, out, ex);
}